// Round 11
// baseline (404.501 us; speedup 1.0000x reference)
//
#include <hip/hip_runtime.h>
#include <stdint.h>

typedef __attribute__((ext_vector_type(8))) short bf16x8;
typedef __attribute__((ext_vector_type(4))) float f32x4;

#define TN 2.45f          // normalized filter threshold (units of s_p)
#define PMARG 0.13f       // exact-rescore pool margin below bf16 rank-32
#define CAP 224
#define SORT2 128

__device__ inline float bf2f(unsigned short u) { return __uint_as_float(((unsigned int)u) << 16); }
__device__ inline unsigned short f2bf(float f) {
    unsigned int x = __float_as_uint(f);
    return (unsigned short)((x + 0x7FFFu + ((x >> 16) & 1u)) >> 16);  // RNE
}

template <typename T>
__device__ inline void gload16(const T* g, T* l) {
    __builtin_amdgcn_global_load_lds((const __attribute__((address_space(1))) void*)g,
                                     (__attribute__((address_space(3))) void*)l, 16, 0, 0);
}

// ---------------- T1: x [16][512][256] -> xT [4096][512] (f32+bf16) + ||x||^2 partials ----------
__global__ __launch_bounds__(256) void t1_x(const float* __restrict__ x, float* __restrict__ xTf,
                                            unsigned short* __restrict__ xTb, float* __restrict__ thrS) {
    __shared__ float tile[64][65];
    int b = blockIdx.z, c0 = blockIdx.x * 64, hw0 = blockIdx.y * 64;
    int tid = threadIdx.x, g = tid >> 6, ln = tid & 63;
    for (int i = 0; i < 16; i++) {
        int cl = g * 16 + i;
        tile[cl][ln] = x[(size_t)(b * 512 + c0 + cl) * 256 + hw0 + ln];
    }
    __syncthreads();
    for (int i = 0; i < 16; i++) {
        int hl = g * 16 + i;
        float v = tile[ln][hl];
        size_t o = (size_t)(b * 256 + hw0 + hl) * 512 + c0 + ln;
        xTf[o] = v;
        xTb[o] = f2bf(v);
        float s = v * v;                       // wave g: all 64 lanes share this hl
        for (int off = 32; off; off >>= 1) s += __shfl_down(s, off, 64);
        if (ln == 0) atomicAdd(&thrS[b * 256 + hw0 + hl], s);
    }
}

// ---------------- T2: enc_w f32 -> bf16 ----------------
__global__ __launch_bounds__(256) void t2_encw(const float* __restrict__ w, unsigned short* __restrict__ wb) {
    size_t i = ((size_t)blockIdx.x * 256 + threadIdx.x) * 8;
    const float4* s = (const float4*)(w + i);
    float4 a = s[0], b = s[1];
    unsigned int p0 = (unsigned)f2bf(a.x) | ((unsigned)f2bf(a.y) << 16);
    unsigned int p1 = (unsigned)f2bf(a.z) | ((unsigned)f2bf(a.w) << 16);
    unsigned int p2 = (unsigned)f2bf(b.x) | ((unsigned)f2bf(b.y) << 16);
    unsigned int p3 = (unsigned)f2bf(b.z) | ((unsigned)f2bf(b.w) << 16);
    *(uint4*)(wb + i) = make_uint4(p0, p1, p2, p3);
}

// ---------------- T3: dec_w [512][16384] -> dec_wT [16384][512] bf16 ----------------
__global__ __launch_bounds__(256) void t3_decw(const float* __restrict__ w, unsigned short* __restrict__ wT) {
    __shared__ float tile[64][65];
    int l0 = blockIdx.x * 64, d0 = blockIdx.y * 64;
    int tid = threadIdx.x, g = tid >> 6, ln = tid & 63;
    for (int i = 0; i < 16; i++) {
        int dl = g * 16 + i;
        tile[dl][ln] = w[(size_t)(d0 + dl) * 16384 + l0 + ln];
    }
    __syncthreads();
    for (int i = 0; i < 16; i++) {
        int ll = g * 16 + i;
        wT[(size_t)(l0 + ll) * 512 + d0 + ln] = f2bf(tile[ln][ll]);
    }
}

// ---- GEMM: 128x256 tile, 512 thr, 3-buf depth-2 counted-vmcnt, T2 swizzle,
//      persistent 4-m-panel loop (one prologue per 32 K-iters, B slice L2-hot) ----
#define SBAR                                   \
    __builtin_amdgcn_sched_barrier(0);         \
    __builtin_amdgcn_s_barrier();              \
    __builtin_amdgcn_sched_barrier(0);
#define VMW6 { asm volatile("s_waitcnt vmcnt(6)" ::: "memory"); __builtin_amdgcn_sched_barrier(0); }
#define VMW0 { asm volatile("s_waitcnt vmcnt(0)" ::: "memory"); __builtin_amdgcn_sched_barrier(0); }

__global__ __launch_bounds__(512) void k_gemm(const unsigned short* __restrict__ xbf,
                                              const unsigned short* __restrict__ wbf,
                                              const float* __restrict__ thrS,
                                              int* __restrict__ cnt, unsigned int* __restrict__ cand) {
    __shared__ __align__(16) unsigned short As[3][128 * 64];  // 3 x 16KB
    __shared__ __align__(16) unsigned short Bs[3][256 * 64];  // 3 x 32KB  (tot 144KB)
    int tid = threadIdx.x, wid = tid >> 6, lane = tid & 63;

    // XCD swizzle (bijective, 512 blocks): XCD k owns 8 consecutive n-panels (2MB B slice)
    int lin = blockIdx.x + blockIdx.y * gridDim.x;   // grid (64 n, 8 m-groups)
    int swz = (lin & 7) * 64 + (lin >> 3);
    int nb = swz >> 3;          // n-panel 0..63
    int mg = swz & 7;           // m-group 0..7 (4 panels each)
    int n0 = nb * 256;
    int wr = wid >> 2, wc = wid & 3;   // 2(M) x 4(N); per-wave 64x64

    f32x4 acc[4][4];
    int srow = lane >> 3;
    int scol = (((lane & 7) ^ (lane >> 3)) << 3);  // involution; read XORs (row&7)<<3

    // tile index it = 0..31: panel pi=it>>3 (m0=(mg*4+pi)*128), K-slice kt=(it&7)*64
#define STAGE(bufi, it2)                                                                          \
    {                                                                                             \
        int pi_ = (it2) >> 3, kt_ = ((it2) & 7) * 64;                                             \
        int m0_ = (mg * 4 + pi_) * 128;                                                           \
        unsigned short* Ad = &As[bufi][0];                                                        \
        unsigned short* Bd = &Bs[bufi][0];                                                        \
        _Pragma("unroll")                                                                         \
        for (int i_ = 0; i_ < 2; i_++) {                                                          \
            int ch_ = wid * 2 + i_;                                                               \
            gload16(xbf + (size_t)(m0_ + ch_ * 8 + srow) * 512 + kt_ + scol, Ad + ch_ * 512);     \
        }                                                                                         \
        _Pragma("unroll")                                                                         \
        for (int i_ = 0; i_ < 4; i_++) {                                                          \
            int ch_ = wid * 4 + i_;                                                               \
            gload16(wbf + (size_t)(n0 + ch_ * 8 + srow) * 512 + kt_ + scol, Bd + ch_ * 512);      \
        }                                                                                         \
    }

    STAGE(0, 0)
    STAGE(1, 1)      // 12 loads/thread in flight (depth 2)
    int cur = 0;
#pragma unroll
    for (int t = 0; t < 32; t++) {
        if (t < 31) VMW6     // tile t landed; tile t+1's 6 loads stay in flight
        else VMW0
        SBAR                  // all waves see tile t; readers of buffer (t+2)%3 retired
        if (t < 30) STAGE((cur + 2) % 3, t + 2)
        if ((t & 7) == 0) {   // panel start: reset accumulator
#pragma unroll
            for (int mi = 0; mi < 4; mi++)
#pragma unroll
                for (int ni = 0; ni < 4; ni++)
#pragma unroll
                    for (int j = 0; j < 4; j++) acc[mi][ni][j] = 0.0f;
        }
        const unsigned short* Ac = &As[cur][0];
        const unsigned short* Bc = &Bs[cur][0];
#pragma unroll
        for (int kk = 0; kk < 2; kk++) {
            int kc = kk * 32 + (lane >> 4) * 8;
            bf16x8 a[4], b[4];
#pragma unroll
            for (int mi = 0; mi < 4; mi++) {
                int row = wr * 64 + mi * 16 + (lane & 15);
                a[mi] = *(const bf16x8*)&Ac[row * 64 + (kc ^ ((row & 7) << 3))];
            }
#pragma unroll
            for (int ni = 0; ni < 4; ni++) {
                int row = wc * 64 + ni * 16 + (lane & 15);
                b[ni] = *(const bf16x8*)&Bc[row * 64 + (kc ^ ((row & 7) << 3))];
            }
#pragma unroll
            for (int mi = 0; mi < 4; mi++)
#pragma unroll
                for (int ni = 0; ni < 4; ni++)
                    acc[mi][ni] = __builtin_amdgcn_mfma_f32_16x16x32_bf16(a[mi], b[ni], acc[mi][ni], 0, 0, 0);
        }
        if ((t & 7) == 7) {   // panel end: filter epilogue (no LDS -> race-free vs pipeline)
            int pi = t >> 3;
            int m0 = (mg * 4 + pi) * 128;
#pragma unroll
            for (int mi = 0; mi < 4; mi++)
#pragma unroll
                for (int j = 0; j < 4; j++) {
                    int pixel = m0 + wr * 64 + mi * 16 + (lane >> 4) * 4 + j;
                    float tv = TN * sqrtf(thrS[pixel] * (1.0f / 512.0f));
#pragma unroll
                    for (int ni = 0; ni < 4; ni++) {
                        float v = acc[mi][ni][j];
                        if (v >= tv) {
                            int lat = n0 + wc * 64 + ni * 16 + (lane & 15);
                            int slot = atomicAdd(&cnt[pixel], 1);
                            if (slot < CAP) cand[pixel * CAP + slot] = ((unsigned)f2bf(v) << 16) | (unsigned)lat;
                        }
                    }
                }
        }
        cur = (cur + 1) % 3;
    }
#undef STAGE
}

// ---- top-32: binary-search bf16 rank-32 threshold, pool-compact, exact seqFMA rescore, sort ----
__global__ __launch_bounds__(256) void k_topk(const float* __restrict__ xTf, const float* __restrict__ enc_w,
                                              const float* __restrict__ enc_b, const int* __restrict__ cnt,
                                              const unsigned int* __restrict__ cand, float* __restrict__ acts_ws,
                                              int* __restrict__ idx_ws, float* __restrict__ out_acts,
                                              float* __restrict__ out_idx) {
    __shared__ __align__(16) float xrow[512];
    __shared__ unsigned long long skey2[SORT2]; // (0xFFFFFFFF-f32bits)<<32 | lat : asc => desc value
    __shared__ int npool;
    int p = blockIdx.x, tid = threadIdx.x;
    for (int i = tid; i < 512; i += 256) xrow[i] = xTf[(size_t)p * 512 + i];
    if (tid < SORT2) skey2[tid] = ~0ull;
    if (tid == 0) npool = 0;
    int c = cnt[p];
    if (c > CAP) c = CAP;
    unsigned int pk = (tid < c) ? cand[p * CAP + tid] : 0u;
    unsigned int bfb = pk >> 16;  // bf16 bits of score (0 if no candidate)
    // binary search: largest T with count(bfb >= T) >= 32
    int lo = 0, hi = 65535;
    for (int it = 0; it < 16; it++) {
        int mid = (lo + hi + 1) >> 1;
        int n = __syncthreads_count(tid < c && bfb >= (unsigned)mid);
        if (n >= 32) lo = mid; else hi = mid - 1;
    }
    float pthr = bf2f((unsigned short)lo) - PMARG;
    __syncthreads();
    // pool: exact rescore (XLA:CPU-matching f32 sequential FMA, c ascending) of candidates
    // within PMARG of the bf16 rank-32 value; compact into skey2 via LDS atomic.
    if (tid < c && bf2f((unsigned short)bfb) >= pthr) {
        int slot = atomicAdd(&npool, 1);
        if (slot < SORT2) {
            int lat = (int)(pk & 16383u);
            const float4* w4 = (const float4*)(enc_w + (size_t)lat * 512);
            const float4* x4 = (const float4*)xrow;
            float acc = 0.0f;
            for (int q = 0; q < 128; q++) {
                float4 w = w4[q];
                float4 xv = x4[q];
                acc = __fmaf_rn(xv.x, w.x, acc);
                acc = __fmaf_rn(xv.y, w.y, acc);
                acc = __fmaf_rn(xv.z, w.z, acc);
                acc = __fmaf_rn(xv.w, w.w, acc);
            }
            float pre = __fadd_rn(acc, enc_b[lat]);
            unsigned long long key;
            if (pre > 0.0f) {
                key = ((unsigned long long)(0xFFFFFFFFu - __float_as_uint(pre)) << 32) | (unsigned)lat;
            } else {
                key = 0xFFFFFFFF00000000ull | (unsigned)lat;
            }
            skey2[slot] = key;
        }
    }
    __syncthreads();
    // bitonic ascending sort of skey2[0..128)
    for (int ks = 2; ks <= SORT2; ks <<= 1) {
        for (int jj = ks >> 1; jj > 0; jj >>= 1) {
            int i = tid;
            if (i < SORT2) {
                int ixj = i ^ jj;
                if (ixj > i) {
                    bool up = ((i & ks) == 0);
                    unsigned long long a = skey2[i], b2 = skey2[ixj];
                    if (up ? (a > b2) : (a < b2)) { skey2[i] = b2; skey2[ixj] = a; }
                }
            }
            __syncthreads();
        }
    }
    if (tid < 32) {
        unsigned long long key = skey2[tid];
        unsigned int fb = 0xFFFFFFFFu - (unsigned int)(key >> 32);
        float act = fmaxf(__uint_as_float(fb), 0.0f);
        int lat = (int)(key & 16383u);
        int b = p >> 8, hw = p & 255;
        acts_ws[p * 32 + tid] = act;
        idx_ws[p * 32 + tid] = lat;
        out_acts[(size_t)b * 8192 + tid * 256 + hw] = act;
        out_idx[(size_t)b * 8192 + tid * 256 + hw] = (float)lat;
    }
}

// ---------------- decode + l2 ----------------
__global__ __launch_bounds__(256) void k_decode(const float* __restrict__ acts_ws, const int* __restrict__ idx_ws,
                                                const unsigned short* __restrict__ dwT,
                                                const float* __restrict__ dec_b, const float* __restrict__ x,
                                                float* __restrict__ out_sae, double* __restrict__ l2acc) {
    __shared__ float sa[32];
    __shared__ int si[32];
    __shared__ double red[256];
    int p = blockIdx.x, tid = threadIdx.x;
    if (tid < 32) {
        sa[tid] = acts_ws[p * 32 + tid];
        si[tid] = idx_ws[p * 32 + tid] & 16383;
    }
    __syncthreads();
    int b = p >> 8, hw = p & 255;
    float a0 = dec_b[tid], a1 = dec_b[tid + 256];
    for (int j = 0; j < 32; j++) {
        float a = sa[j];
        const unsigned short* r = dwT + (size_t)si[j] * 512;
        a0 += a * bf2f(r[tid]);
        a1 += a * bf2f(r[tid + 256]);
    }
    size_t o0 = (size_t)b * 131072 + (size_t)tid * 256 + hw;
    size_t o1 = o0 + 65536;
    out_sae[o0] = a0;
    out_sae[o1] = a1;
    float e0 = a0 - x[o0], e1 = a1 - x[o1];
    red[tid] = (double)e0 * e0 + (double)e1 * e1;
    __syncthreads();
    for (int s = 128; s; s >>= 1) {
        if (tid < s) red[tid] += red[tid + s];
        __syncthreads();
    }
    if (tid == 0) atomicAdd(l2acc, red[0]);
}

// ---------------- per-channel stats ----------------
__global__ __launch_bounds__(256) void k_chan(const float* __restrict__ x, double* __restrict__ S,
                                              double* __restrict__ Q) {
    __shared__ double rs[256], rq[256];
    int c = blockIdx.x, tid = threadIdx.x;
    double s = 0, q = 0;
    for (int b = 0; b < 16; b++) {
        float v = x[(size_t)b * 131072 + (size_t)c * 256 + tid];
        s += v;
        q += (double)v * v;
    }
    rs[tid] = s;
    rq[tid] = q;
    __syncthreads();
    for (int st = 128; st; st >>= 1) {
        if (tid < st) { rs[tid] += rs[tid + st]; rq[tid] += rq[tid + st]; }
        __syncthreads();
    }
    if (tid == 0) { S[c] = rs[0]; Q[c] = rq[0]; }
}

// ---------------- finalize fvu ----------------
__global__ __launch_bounds__(256) void k_fin(const double* __restrict__ l2, const double* __restrict__ S,
                                             const double* __restrict__ Q, float* __restrict__ out_sc) {
    __shared__ double red[256];
    int tid = threadIdx.x;
    double tv = 0;
    for (int c = tid; c < 512; c += 256) tv += Q[c] - S[c] * S[c] * (1.0 / 4096.0);
    red[tid] = tv;
    __syncthreads();
    for (int s = 128; s; s >>= 1) {
        if (tid < s) red[tid] += red[tid + s];
        __syncthreads();
    }
    if (tid == 0) {
        double fvu = l2[0] / red[0];
        out_sc[0] = (float)fvu;
        out_sc[1] = 0.0f;
        out_sc[2] = 0.0f;
    }
}

extern "C" void kernel_launch(void* const* d_in, const int* in_sizes, int n_in,
                              void* d_out, int out_size, void* d_ws, size_t ws_size,
                              hipStream_t stream) {
    const float* x = (const float*)d_in[0];
    const float* enc_w = (const float*)d_in[1];
    const float* enc_b = (const float*)d_in[2];
    const float* dec_w = (const float*)d_in[3];
    const float* dec_b = (const float*)d_in[4];
    (void)in_sizes; (void)n_in; (void)out_size; (void)ws_size;

    char* ws = (char*)d_ws;
    float* xTf = (float*)ws;                                  //  8 MB
    unsigned short* xTb = (unsigned short*)(ws + 8388608);    //  4 MB
    unsigned short* ewb = (unsigned short*)(ws + 12582912);   // 16 MB
    unsigned short* dwT = (unsigned short*)(ws + 29360128);   // 16 MB
    unsigned int* cand = (unsigned int*)(ws + 46137344);      //  3.67 MB (4096*224*4)
    int* cnt = (int*)(ws + 49807360);                         // 16 KB
    float* thrS = (float*)(ws + 49823744);                    // 16 KB
    float* acts_ws = (float*)(ws + 49840128);                 // 512 KB
    int* idx_ws = (int*)(ws + 50364416);                      // 512 KB
    double* S = (double*)(ws + 50888704);                     //  4 KB
    double* Q = (double*)(ws + 50892800);                     //  4 KB
    double* l2 = (double*)(ws + 50896896);                    //  8 B

    float* out = (float*)d_out;   // reference outputs are float32
    float* out_sae = out;
    float* out_acts = out + 2097152;
    float* out_idx = out + 2228224;
    float* out_sc = out + 2359296;

    hipMemsetAsync(cnt, 0, 4096 * 4, stream);
    hipMemsetAsync(thrS, 0, 4096 * 4, stream);
    hipMemsetAsync(l2, 0, 8, stream);

    t1_x<<<dim3(8, 4, 16), 256, 0, stream>>>(x, xTf, xTb, thrS);
    t2_encw<<<4096, 256, 0, stream>>>(enc_w, ewb);
    t3_decw<<<dim3(256, 8), 256, 0, stream>>>(dec_w, dwT);
    k_gemm<<<dim3(64, 8), 512, 0, stream>>>(xTb, ewb, thrS, cnt, cand);
    k_topk<<<4096, 256, 0, stream>>>(xTf, enc_w, enc_b, cnt, cand, acts_ws, idx_ws, out_acts, out_idx);
    k_decode<<<4096, 256, 0, stream>>>(acts_ws, idx_ws, dwT, dec_b, x, out_sae, l2);
    k_chan<<<512, 256, 0, stream>>>(x, S, Q);
    k_fin<<<1, 256, 0, stream>>>(l2, S, Q, out_sc);
}

// Round 12
// 348.926 us; speedup vs baseline: 1.1593x; 1.1593x over previous
//
#include <hip/hip_runtime.h>
#include <stdint.h>

typedef __attribute__((ext_vector_type(8))) short bf16x8;
typedef __attribute__((ext_vector_type(4))) float f32x4;

#define TN 2.45f          // normalized filter threshold (units of s_p)
#define PMARG 0.13f       // exact-rescore pool margin below bf16 rank-32
#define CAP 224
#define SORT2 128

__device__ inline float bf2f(unsigned short u) { return __uint_as_float(((unsigned int)u) << 16); }
__device__ inline unsigned short f2bf(float f) {
    unsigned int x = __float_as_uint(f);
    return (unsigned short)((x + 0x7FFFu + ((x >> 16) & 1u)) >> 16);  // RNE
}

template <typename T>
__device__ inline void gload16(const T* g, T* l) {
    __builtin_amdgcn_global_load_lds((const __attribute__((address_space(1))) void*)g,
                                     (__attribute__((address_space(3))) void*)l, 16, 0, 0);
}

// ---- T1: x [16][512][256] -> xT [4096][512] (f32+bf16) + ||x_p||^2 + per-channel S/Q ----
__global__ __launch_bounds__(256) void t1_x(const float* __restrict__ x, float* __restrict__ xTf,
                                            unsigned short* __restrict__ xTb, float* __restrict__ thrS,
                                            double* __restrict__ S, double* __restrict__ Q) {
    __shared__ float tile[64][65];
    int b = blockIdx.z, c0 = blockIdx.x * 64, hw0 = blockIdx.y * 64;
    int tid = threadIdx.x, g = tid >> 6, ln = tid & 63;
    for (int i = 0; i < 16; i++) {
        int cl = g * 16 + i;
        tile[cl][ln] = x[(size_t)(b * 512 + c0 + cl) * 256 + hw0 + ln];
    }
    __syncthreads();
    float s1 = 0.0f, s2 = 0.0f;  // channel c0+ln over this wave's 16 hw positions
    for (int i = 0; i < 16; i++) {
        int hl = g * 16 + i;
        float v = tile[ln][hl];
        size_t o = (size_t)(b * 256 + hw0 + hl) * 512 + c0 + ln;
        xTf[o] = v;
        xTb[o] = f2bf(v);
        s1 += v;
        s2 += v * v;
        float s = v * v;  // per-pixel ||x||^2 partial (lanes = channels)
        for (int off = 32; off; off >>= 1) s += __shfl_down(s, off, 64);
        if (ln == 0) atomicAdd(&thrS[b * 256 + hw0 + hl], s);
    }
    atomicAdd(&S[c0 + ln], (double)s1);
    atomicAdd(&Q[c0 + ln], (double)s2);
}

// ---------------- T2: enc_w f32 -> bf16 ----------------
__global__ __launch_bounds__(256) void t2_encw(const float* __restrict__ w, unsigned short* __restrict__ wb) {
    size_t i = ((size_t)blockIdx.x * 256 + threadIdx.x) * 8;
    const float4* s = (const float4*)(w + i);
    float4 a = s[0], b = s[1];
    unsigned int p0 = (unsigned)f2bf(a.x) | ((unsigned)f2bf(a.y) << 16);
    unsigned int p1 = (unsigned)f2bf(a.z) | ((unsigned)f2bf(a.w) << 16);
    unsigned int p2 = (unsigned)f2bf(b.x) | ((unsigned)f2bf(b.y) << 16);
    unsigned int p3 = (unsigned)f2bf(b.z) | ((unsigned)f2bf(b.w) << 16);
    *(uint4*)(wb + i) = make_uint4(p0, p1, p2, p3);
}

// ---------------- T3: dec_w [512][16384] -> dec_wT [16384][512] bf16 ----------------
__global__ __launch_bounds__(256) void t3_decw(const float* __restrict__ w, unsigned short* __restrict__ wT) {
    __shared__ float tile[64][65];
    int l0 = blockIdx.x * 64, d0 = blockIdx.y * 64;
    int tid = threadIdx.x, g = tid >> 6, ln = tid & 63;
    for (int i = 0; i < 16; i++) {
        int dl = g * 16 + i;
        tile[dl][ln] = w[(size_t)(d0 + dl) * 16384 + l0 + ln];
    }
    __syncthreads();
    for (int i = 0; i < 16; i++) {
        int ll = g * 16 + i;
        wT[(size_t)(l0 + ll) * 512 + d0 + ln] = f2bf(tile[ln][ll]);
    }
}

// ---- GEMM (R8-proven): 128x256, 512 thr, 3-buf depth-2, counted vmcnt(6), T2 swizzle ----
#define SBAR                                   \
    __builtin_amdgcn_sched_barrier(0);         \
    __builtin_amdgcn_s_barrier();              \
    __builtin_amdgcn_sched_barrier(0);
#define VMW6 { asm volatile("s_waitcnt vmcnt(6)" ::: "memory"); __builtin_amdgcn_sched_barrier(0); }
#define VMW0 { asm volatile("s_waitcnt vmcnt(0)" ::: "memory"); __builtin_amdgcn_sched_barrier(0); }

__global__ __launch_bounds__(512) void k_gemm(const unsigned short* __restrict__ xbf,
                                              const unsigned short* __restrict__ wbf,
                                              const float* __restrict__ thrS,
                                              int* __restrict__ cnt, unsigned int* __restrict__ cand) {
    __shared__ __align__(16) unsigned short As[3][128 * 64];  // 3 x 16KB
    __shared__ __align__(16) unsigned short Bs[3][256 * 64];  // 3 x 32KB  (tot 144KB)
    int tid = threadIdx.x, wid = tid >> 6, lane = tid & 63;

    // XCD swizzle (bijective, 2048 blocks): each XCD owns 8 consecutive n-panels (2MB B slice)
    int lin = blockIdx.x + blockIdx.y * gridDim.x;   // grid (64 n, 32 m)
    int swz = (lin & 7) * 256 + (lin >> 3);
    int bx = swz >> 5;          // n-block 0..63
    int by = swz & 31;          // m-block 0..31
    int m0 = by * 128, n0 = bx * 256;
    int wr = wid >> 2, wc = wid & 3;   // 2(M) x 4(N); per-wave 64x64

    f32x4 acc[4][4];
#pragma unroll
    for (int mi = 0; mi < 4; mi++)
#pragma unroll
        for (int ni = 0; ni < 4; ni++)
#pragma unroll
            for (int j = 0; j < 4; j++) acc[mi][ni][j] = 0.0f;

    int srow = lane >> 3;
    int scol = (((lane & 7) ^ (lane >> 3)) << 3);  // involution; read side XORs (row&7)<<3

#define STAGE(bufi, kt)                                                                           \
    {                                                                                             \
        unsigned short* Ad = &As[bufi][0];                                                        \
        unsigned short* Bd = &Bs[bufi][0];                                                        \
        _Pragma("unroll")                                                                         \
        for (int i_ = 0; i_ < 2; i_++) {                                                          \
            int ch_ = wid * 2 + i_;                                                               \
            gload16(xbf + (size_t)(m0 + ch_ * 8 + srow) * 512 + (kt) + scol, Ad + ch_ * 512);     \
        }                                                                                         \
        _Pragma("unroll")                                                                         \
        for (int i_ = 0; i_ < 4; i_++) {                                                          \
            int ch_ = wid * 4 + i_;                                                               \
            gload16(wbf + (size_t)(n0 + ch_ * 8 + srow) * 512 + (kt) + scol, Bd + ch_ * 512);     \
        }                                                                                         \
    }

    STAGE(0, 0)
    STAGE(1, 64)     // depth-2 prefetch in flight
    int cur = 0;
#pragma unroll
    for (int t = 0; t < 8; t++) {
        if (t < 7) VMW6      // tile t landed; tile t+1's 6 loads stay in flight
        else VMW0
        SBAR                  // all waves have tile t; readers of buffer (t+2)%3 retired
        if (t < 6) STAGE((cur + 2) % 3, (t + 2) * 64)
        const unsigned short* Ac = &As[cur][0];
        const unsigned short* Bc = &Bs[cur][0];
#pragma unroll
        for (int kk = 0; kk < 2; kk++) {
            int kc = kk * 32 + (lane >> 4) * 8;
            bf16x8 a[4], b[4];
#pragma unroll
            for (int mi = 0; mi < 4; mi++) {
                int row = wr * 64 + mi * 16 + (lane & 15);
                a[mi] = *(const bf16x8*)&Ac[row * 64 + (kc ^ ((row & 7) << 3))];
            }
#pragma unroll
            for (int ni = 0; ni < 4; ni++) {
                int row = wc * 64 + ni * 16 + (lane & 15);
                b[ni] = *(const bf16x8*)&Bc[row * 64 + (kc ^ ((row & 7) << 3))];
            }
#pragma unroll
            for (int mi = 0; mi < 4; mi++)
#pragma unroll
                for (int ni = 0; ni < 4; ni++)
                    acc[mi][ni] = __builtin_amdgcn_mfma_f32_16x16x32_bf16(a[mi], b[ni], acc[mi][ni], 0, 0, 0);
        }
        cur = (cur + 1) % 3;
    }
#undef STAGE

    // filter epilogue (outside the pipeline -> vmcnt-clean)
#pragma unroll
    for (int mi = 0; mi < 4; mi++)
#pragma unroll
        for (int j = 0; j < 4; j++) {
            int pixel = m0 + wr * 64 + mi * 16 + (lane >> 4) * 4 + j;
            float tv = TN * sqrtf(thrS[pixel] * (1.0f / 512.0f));
#pragma unroll
            for (int ni = 0; ni < 4; ni++) {
                float v = acc[mi][ni][j];
                if (v >= tv) {
                    int lat = n0 + wc * 64 + ni * 16 + (lane & 15);
                    int slot = atomicAdd(&cnt[pixel], 1);
                    if (slot < CAP) cand[pixel * CAP + slot] = ((unsigned)f2bf(v) << 16) | (unsigned)lat;
                }
            }
        }
}

// ---- top-32 + decode fused: binary-search bf16 rank-32, exact seqFMA rescore pool, sort,
//      then sparse decode + l2 using xrow already in LDS ----
__global__ __launch_bounds__(256) void k_topk(const float* __restrict__ xTf, const float* __restrict__ enc_w,
                                              const float* __restrict__ enc_b, const int* __restrict__ cnt,
                                              const unsigned int* __restrict__ cand,
                                              const unsigned short* __restrict__ dwT,
                                              const float* __restrict__ dec_b,
                                              float* __restrict__ out_acts, float* __restrict__ out_idx,
                                              float* __restrict__ out_sae, double* __restrict__ l2acc) {
    __shared__ __align__(16) float xrow[512];
    __shared__ unsigned long long skey2[SORT2]; // (0xFFFFFFFF-f32bits)<<32 | lat : asc => desc value
    __shared__ int npool;
    __shared__ float sa[32];
    __shared__ int si[32];
    __shared__ double red[256];
    int p = blockIdx.x, tid = threadIdx.x;
    for (int i = tid; i < 512; i += 256) xrow[i] = xTf[(size_t)p * 512 + i];
    if (tid < SORT2) skey2[tid] = ~0ull;
    if (tid == 0) npool = 0;
    int c = cnt[p];
    if (c > CAP) c = CAP;
    unsigned int pk = (tid < c) ? cand[p * CAP + tid] : 0u;
    unsigned int bfb = pk >> 16;  // bf16 bits of score (0 if no candidate)
    // binary search: largest T with count(bfb >= T) >= 32
    int lo = 0, hi = 65535;
    for (int it = 0; it < 16; it++) {
        int mid = (lo + hi + 1) >> 1;
        int n = __syncthreads_count(tid < c && bfb >= (unsigned)mid);
        if (n >= 32) lo = mid; else hi = mid - 1;
    }
    float pthr = bf2f((unsigned short)lo) - PMARG;
    __syncthreads();
    // exact rescore (XLA:CPU-matching f32 sequential FMA, c ascending) of near-top pool
    if (tid < c && bf2f((unsigned short)bfb) >= pthr) {
        int slot = atomicAdd(&npool, 1);
        if (slot < SORT2) {
            int lat = (int)(pk & 16383u);
            const float4* w4 = (const float4*)(enc_w + (size_t)lat * 512);
            const float4* x4 = (const float4*)xrow;
            float acc = 0.0f;
            for (int q = 0; q < 128; q++) {
                float4 w = w4[q];
                float4 xv = x4[q];
                acc = __fmaf_rn(xv.x, w.x, acc);
                acc = __fmaf_rn(xv.y, w.y, acc);
                acc = __fmaf_rn(xv.z, w.z, acc);
                acc = __fmaf_rn(xv.w, w.w, acc);
            }
            float pre = __fadd_rn(acc, enc_b[lat]);
            unsigned long long key;
            if (pre > 0.0f) {
                key = ((unsigned long long)(0xFFFFFFFFu - __float_as_uint(pre)) << 32) | (unsigned)lat;
            } else {
                key = 0xFFFFFFFF00000000ull | (unsigned)lat;
            }
            skey2[slot] = key;
        }
    }
    __syncthreads();
    // bitonic ascending sort of skey2[0..128)
    for (int ks = 2; ks <= SORT2; ks <<= 1) {
        for (int jj = ks >> 1; jj > 0; jj >>= 1) {
            int i = tid;
            if (i < SORT2) {
                int ixj = i ^ jj;
                if (ixj > i) {
                    bool up = ((i & ks) == 0);
                    unsigned long long a = skey2[i], b2 = skey2[ixj];
                    if (up ? (a > b2) : (a < b2)) { skey2[i] = b2; skey2[ixj] = a; }
                }
            }
            __syncthreads();
        }
    }
    int b = p >> 8, hw = p & 255;
    if (tid < 32) {
        unsigned long long key = skey2[tid];
        unsigned int fb = 0xFFFFFFFFu - (unsigned int)(key >> 32);
        float act = fmaxf(__uint_as_float(fb), 0.0f);
        int lat = (int)(key & 16383u);
        sa[tid] = act;
        si[tid] = lat;
        out_acts[(size_t)b * 8192 + tid * 256 + hw] = act;
        out_idx[(size_t)b * 8192 + tid * 256 + hw] = (float)lat;
    }
    __syncthreads();
    // ---- fused decode + l2 (xrow holds x[b,:,hw] exactly) ----
    float a0 = dec_b[tid], a1 = dec_b[tid + 256];
    for (int j = 0; j < 32; j++) {
        float a = sa[j];
        const unsigned short* r = dwT + (size_t)si[j] * 512;
        a0 += a * bf2f(r[tid]);
        a1 += a * bf2f(r[tid + 256]);
    }
    size_t o0 = (size_t)b * 131072 + (size_t)tid * 256 + hw;
    size_t o1 = o0 + 65536;
    out_sae[o0] = a0;
    out_sae[o1] = a1;
    float e0 = a0 - xrow[tid], e1 = a1 - xrow[tid + 256];
    red[tid] = (double)e0 * e0 + (double)e1 * e1;
    __syncthreads();
    for (int s = 128; s; s >>= 1) {
        if (tid < s) red[tid] += red[tid + s];
        __syncthreads();
    }
    if (tid == 0) atomicAdd(l2acc, red[0]);
}

// ---------------- finalize fvu ----------------
__global__ __launch_bounds__(256) void k_fin(const double* __restrict__ l2, const double* __restrict__ S,
                                             const double* __restrict__ Q, float* __restrict__ out_sc) {
    __shared__ double red[256];
    int tid = threadIdx.x;
    double tv = 0;
    for (int c = tid; c < 512; c += 256) tv += Q[c] - S[c] * S[c] * (1.0 / 4096.0);
    red[tid] = tv;
    __syncthreads();
    for (int s = 128; s; s >>= 1) {
        if (tid < s) red[tid] += red[tid + s];
        __syncthreads();
    }
    if (tid == 0) {
        double fvu = l2[0] / red[0];
        out_sc[0] = (float)fvu;
        out_sc[1] = 0.0f;
        out_sc[2] = 0.0f;
    }
}

extern "C" void kernel_launch(void* const* d_in, const int* in_sizes, int n_in,
                              void* d_out, int out_size, void* d_ws, size_t ws_size,
                              hipStream_t stream) {
    const float* x = (const float*)d_in[0];
    const float* enc_w = (const float*)d_in[1];
    const float* enc_b = (const float*)d_in[2];
    const float* dec_w = (const float*)d_in[3];
    const float* dec_b = (const float*)d_in[4];
    (void)in_sizes; (void)n_in; (void)out_size; (void)ws_size;

    char* ws = (char*)d_ws;
    float* xTf = (float*)ws;                                  //  8 MB
    unsigned short* xTb = (unsigned short*)(ws + 8388608);    //  4 MB
    unsigned short* ewb = (unsigned short*)(ws + 12582912);   // 16 MB
    unsigned short* dwT = (unsigned short*)(ws + 29360128);   // 16 MB
    unsigned int* cand = (unsigned int*)(ws + 46137344);      //  3.67 MB (4096*224*4)
    // contiguous zero-init region: cnt | thrS | S | Q | l2
    int* cnt = (int*)(ws + 49807360);                         // 16 KB
    float* thrS = (float*)(ws + 49823744);                    // 16 KB
    double* S = (double*)(ws + 49840128);                     //  4 KB
    double* Q = (double*)(ws + 49844224);                     //  4 KB
    double* l2 = (double*)(ws + 49848320);                    //  8 B

    float* out = (float*)d_out;   // reference outputs are float32
    float* out_sae = out;
    float* out_acts = out + 2097152;
    float* out_idx = out + 2228224;
    float* out_sc = out + 2359296;

    hipMemsetAsync(cnt, 0, 16384 + 16384 + 4096 + 4096 + 8, stream);

    t1_x<<<dim3(8, 4, 16), 256, 0, stream>>>(x, xTf, xTb, thrS, S, Q);
    t2_encw<<<4096, 256, 0, stream>>>(enc_w, ewb);
    t3_decw<<<dim3(256, 8), 256, 0, stream>>>(dec_w, dwT);
    k_gemm<<<dim3(64, 32), 512, 0, stream>>>(xTb, ewb, thrS, cnt, cand);
    k_topk<<<4096, 256, 0, stream>>>(xTf, enc_w, enc_b, cnt, cand, dwT, dec_b,
                                     out_acts, out_idx, out_sae, l2);
    k_fin<<<1, 256, 0, stream>>>(l2, S, Q, out_sc);
}